// Round 2
// baseline (625.552 us; speedup 1.0000x reference)
//
#include <hip/hip_runtime.h>
#include <hip/hip_bf16.h>

constexpr int NB = 4, NT = 512, NE = 1024, NW = 64, NH = 16, NDK = 64;
constexpr int NBT = NB * NT;   // 2048 token rows

// out[r, j] = sum_e X[r, e] * Wt[e, j] + bias[j]
// grid: (NE/256 col chunks, NBT/ROWS row chunks), block: 256
template <int ROWS>
__global__ void gemm_bias_kernel(const float* __restrict__ X,
                                 const float* __restrict__ Wt,
                                 const float* __restrict__ bias,
                                 float* __restrict__ out) {
    const int j  = blockIdx.x * 256 + threadIdx.x;
    const int r0 = blockIdx.y * ROWS;

    __shared__ float xs[ROWS][NE];
    for (int i = threadIdx.x; i < ROWS * NE; i += 256) {
        int rr = i >> 10;          // / NE
        int ee = i & (NE - 1);     // % NE
        xs[rr][ee] = X[(size_t)(r0 + rr) * NE + ee];
    }
    __syncthreads();

    float acc[ROWS];
#pragma unroll
    for (int rr = 0; rr < ROWS; rr++) acc[rr] = 0.f;

    for (int e = 0; e < NE; e++) {
        float w = Wt[(size_t)e * NE + j];
#pragma unroll
        for (int rr = 0; rr < ROWS; rr++) acc[rr] += xs[rr][e] * w;
    }

    float bb = bias[j];
#pragma unroll
    for (int rr = 0; rr < ROWS; rr++)
        out[(size_t)(r0 + rr) * NE + j] = acc[rr] + bb;
}

// One block per (b,t); all NH heads.
// Y holds x@Wq+bq rows (query row t AND key rows src(t,w));
// Z holds x@Wv+bv rows. M[bt, h*NDK+d] gets the merged attention output.
__global__ void attn_kernel(const float* __restrict__ Y,
                            const float* __restrict__ Z,
                            float* __restrict__ M) {
    const int bt = blockIdx.x;
    const int b  = bt >> 9;        // / NT
    const int t  = bt & (NT - 1);  // % NT
    const int tid = threadIdx.x;

    __shared__ float yt[NE];        // query row
    __shared__ float sc[NH][NW];    // scores -> probs

    const float* Yb = Y + (size_t)b * NT * NE;
    const float* Zb = Z + (size_t)b * NT * NE;

    for (int i = tid; i < NE; i += 256) yt[i] = Yb[(size_t)t * NE + i];
    __syncthreads();

    const int h  = tid & 15;   // head; adjacent lanes -> adjacent addresses
    const int wg = tid >> 4;   // group of 4 window slots / 4 d's

    // scores[h][w] = (1/32) * sum_d yt[d*16+h] * Y[b, src, d*16+h]
#pragma unroll
    for (int wi = 0; wi < 4; wi++) {
        int w = wg * 4 + wi;
        int src = t - NW / 2 + w;
        src = src < 0 ? 0 : (src > NT - 1 ? NT - 1 : src);
        const float* yr = Yb + (size_t)src * NE;
        float acc = 0.f;
#pragma unroll
        for (int d = 0; d < NDK; d++)
            acc += yt[d * NH + h] * yr[d * NH + h];
        sc[h][w] = acc * (1.0f / 32.0f);   // 1/sqrt(E)
    }
    __syncthreads();

    // serial per-head softmax over NW=64 (threads 0..15)
    if (tid < NH) {
        float mx = -1e30f;
        for (int w = 0; w < NW; w++) mx = fmaxf(mx, sc[tid][w]);
        float s = 0.f;
        for (int w = 0; w < NW; w++) {
            float p = __expf(sc[tid][w] - mx);
            sc[tid][w] = p;
            s += p;
        }
        float inv = 1.f / s;
        for (int w = 0; w < NW; w++) sc[tid][w] *= inv;
    }
    __syncthreads();

    // out[h][d] = sum_w probs[h][w] * Z[b, src, d*16+h]; merged H-major
    float* Mrow = M + (size_t)bt * NE;
#pragma unroll
    for (int di = 0; di < 4; di++) {
        int d = wg * 4 + di;
        float acc = 0.f;
        for (int w = 0; w < NW; w++) {
            int src = t - NW / 2 + w;
            src = src < 0 ? 0 : (src > NT - 1 ? NT - 1 : src);
            acc += sc[h][w] * Zb[(size_t)src * NE + d * NH + h];
        }
        Mrow[h * NDK + d] = acc;
    }
}

extern "C" void kernel_launch(void* const* d_in, const int* in_sizes, int n_in,
                              void* d_out, int out_size, void* d_ws, size_t ws_size,
                              hipStream_t stream) {
    const float* x  = (const float*)d_in[0];
    // d_in[1] = position_mask: unused (window gather computed analytically)
    const float* Wq = (const float*)d_in[2];
    const float* bq = (const float*)d_in[3];
    const float* Wv = (const float*)d_in[4];
    const float* bv = (const float*)d_in[5];
    const float* Wo = (const float*)d_in[6];
    const float* bo = (const float*)d_in[7];
    float* outp = (float*)d_out;

    // workspace: Y (f32, 8MB) | Z (f32, 8MB) | M (f32, 8MB)
    float* Yw = (float*)d_ws;
    float* Zw = Yw + (size_t)NBT * NE;
    float* Mw = Zw + (size_t)NBT * NE;

    dim3 blk(256);
    dim3 g1(NE / 256, NBT / 4);
    gemm_bias_kernel<4><<<g1, blk, 0, stream>>>(x, Wq, bq, Yw);
    gemm_bias_kernel<4><<<g1, blk, 0, stream>>>(x, Wv, bv, Zw);
    attn_kernel<<<dim3(NBT), blk, 0, stream>>>(Yw, Zw, Mw);
    gemm_bias_kernel<4><<<g1, blk, 0, stream>>>(Mw, Wo, bo, outp);
}

// Round 3
// 208.712 us; speedup vs baseline: 2.9972x; 2.9972x over previous
//
#include <hip/hip_runtime.h>
#include <hip/hip_bf16.h>

typedef __attribute__((ext_vector_type(8))) short short8;
typedef __attribute__((ext_vector_type(4))) float f32x4;

constexpr int NB = 4, NT = 512, NE = 1024, NW = 64, NH = 16, NDK = 64;
constexpr int NBT = NB * NT;   // 2048 token rows

__device__ inline short f2bf(float f) {
    __hip_bfloat16 h = __float2bfloat16(f);
    return __builtin_bit_cast(short, h);
}
__device__ inline float bf2f(short s) {
    unsigned u = ((unsigned)(unsigned short)s) << 16;
    return __builtin_bit_cast(float, u);
}

// ---------------- cast x: f32 -> bf16 (row-major unchanged) ----------------
__global__ __launch_bounds__(256) void cast_x_kernel(const float* __restrict__ X,
                                                     short* __restrict__ Xb) {
    size_t idx = (size_t)blockIdx.x * 256 + threadIdx.x;   // 8 elems per thread
    const float4* p = (const float4*)(X + idx * 8);
    float4 a = p[0], b = p[1];
    short8 v;
    v[0] = f2bf(a.x); v[1] = f2bf(a.y); v[2] = f2bf(a.z); v[3] = f2bf(a.w);
    v[4] = f2bf(b.x); v[5] = f2bf(b.y); v[6] = f2bf(b.z); v[7] = f2bf(b.w);
    *(short8*)(Xb + idx * 8) = v;
}

// ------------- cast+transpose W: f32 [E][N] -> bf16 [N][E], optional col perm
// PERM: output row jp = (j&15)*64 + (j>>4)  (j = d*16+h  ->  jp = h*64+d)
template <bool PERM>
__global__ __launch_bounds__(256) void transpose_w_kernel(const float* __restrict__ W,
                                                          short* __restrict__ WT) {
    __shared__ float tile[64][65];
    const int e0 = blockIdx.y * 64, j0 = blockIdx.x * 64;
    const int el = threadIdx.x & 63, grp = threadIdx.x >> 6;
    for (int i = grp; i < 64; i += 4)
        tile[i][el] = W[(size_t)(e0 + i) * NE + j0 + el];
    __syncthreads();
    for (int it = grp; it < 64; it += 4) {
        int j = j0 + it;
        int jp = PERM ? ((j & 15) * 64 + (j >> 4)) : j;
        WT[(size_t)jp * NE + e0 + el] = f2bf(tile[el][it]);
    }
}

// ---------------- MFMA GEMM: out[r][jp] = sum_e X[r][e]*WT[jp][e] + bias ----
// X bf16 [NBT][NE]; WT bf16 [NE][NE] (row jp, col e); 128x128 tile, BK=64.
template <bool PERM_BIAS, bool OUT_BF16>
__global__ __launch_bounds__(256) void mfma_gemm_kernel(const short* __restrict__ X,
                                                        const short* __restrict__ WT,
                                                        const float* __restrict__ bias,
                                                        void* __restrict__ outv) {
    __shared__ short As[128 * 64];
    __shared__ short Bs[128 * 64];
    const int tid = threadIdx.x;
    const int lane = tid & 63, wid = tid >> 6;
    const int r0 = blockIdx.y * 128, c0 = blockIdx.x * 128;
    const int wr = (wid >> 1) * 64, wc = (wid & 1) * 64;

    f32x4 acc[4][4];
#pragma unroll
    for (int m = 0; m < 4; m++)
#pragma unroll
        for (int n = 0; n < 4; n++) acc[m][n] = (f32x4){0.f, 0.f, 0.f, 0.f};

    short8 pfA[4], pfB[4];
    // slot -> (row, swizzled chunk); logical chunk c = cp ^ (row&7)
    auto load_tiles = [&](int k0) {
#pragma unroll
        for (int rd = 0; rd < 4; rd++) {
            int slot = rd * 4096 + tid * 16;       // byte offset in 16KB tile
            int row  = slot >> 7;                  // /128B
            int cp   = (slot >> 4) & 7;
            int c    = cp ^ (row & 7);
            pfA[rd] = *(const short8*)(X  + (size_t)(r0 + row) * NE + k0 + c * 8);
            pfB[rd] = *(const short8*)(WT + (size_t)(c0 + row) * NE + k0 + c * 8);
        }
    };

    load_tiles(0);
    for (int k0 = 0; k0 < NE; k0 += 64) {
        __syncthreads();   // previous compute done before overwrite
#pragma unroll
        for (int rd = 0; rd < 4; rd++) {
            int slot = rd * 4096 + tid * 16;
            *(short8*)((char*)As + slot) = pfA[rd];
            *(short8*)((char*)Bs + slot) = pfB[rd];
        }
        __syncthreads();
        if (k0 + 64 < NE) load_tiles(k0 + 64);   // prefetch hides under MFMA

#pragma unroll
        for (int kk = 0; kk < 2; kk++) {
            short8 af[4], bf[4];
            const int cidx = kk * 4 + (lane >> 4);
#pragma unroll
            for (int m = 0; m < 4; m++) {
                int row = wr + m * 16 + (lane & 15);
                af[m] = *(const short8*)((char*)As + row * 128 + ((cidx ^ (row & 7)) * 16));
            }
#pragma unroll
            for (int n = 0; n < 4; n++) {
                int row = wc + n * 16 + (lane & 15);
                bf[n] = *(const short8*)((char*)Bs + row * 128 + ((cidx ^ (row & 7)) * 16));
            }
#pragma unroll
            for (int m = 0; m < 4; m++)
#pragma unroll
                for (int n = 0; n < 4; n++)
                    acc[m][n] = __builtin_amdgcn_mfma_f32_16x16x32_bf16(af[m], bf[n], acc[m][n], 0, 0, 0);
        }
    }

    short* outS = (short*)outv;
    float* outF = (float*)outv;
#pragma unroll
    for (int m = 0; m < 4; m++)
#pragma unroll
        for (int n = 0; n < 4; n++) {
            int col  = c0 + wc + n * 16 + (lane & 15);
            int bsrc = PERM_BIAS ? ((col & 63) * 16 + (col >> 6)) : col;
            float bb = bias[bsrc];
#pragma unroll
            for (int r = 0; r < 4; r++) {
                int row = r0 + wr + m * 16 + (lane >> 4) * 4 + r;
                float val = acc[m][n][r] + bb;
                if (OUT_BF16) outS[(size_t)row * NE + col] = f2bf(val);
                else          outF[(size_t)row * NE + col] = val;
            }
        }
}

// ---------------- windowed attention, head-major layout ----------------
// Y,Z bf16 [B*T][NE] with column jp = h*64+d. Block = (t-tile 64, h, b).
// Stages K/V rows [t0-32, t0+96) (clamped) for one head into LDS f32.
__global__ __launch_bounds__(256) void attn_kernel(const short* __restrict__ Y,
                                                   const short* __restrict__ Z,
                                                   short* __restrict__ M) {
    __shared__ float KS[128][66];
    __shared__ float VS[128][66];
    __shared__ float SC[64][65];
    __shared__ float RED[64][8];

    const int t0 = blockIdx.x * 64;
    const int h  = blockIdx.y;
    const int b  = blockIdx.z;
    const int tid = threadIdx.x;
    const int tl = tid & 63;    // local t
    const int qq = tid >> 6;    // quarter (= wave id)

    // stage K (= Y rows, also serves Q) and V windows: 128 rows x 64 d
    for (int idx = tid; idx < 1024; idx += 256) {
        int row = idx >> 3, c = idx & 7;
        int ts = t0 - 32 + row;
        ts = ts < 0 ? 0 : (ts > NT - 1 ? NT - 1 : ts);
        size_t base = ((size_t)b * NT + ts) * NE + h * 64 + c * 8;
        short8 kv = *(const short8*)(Y + base);
        short8 vv = *(const short8*)(Z + base);
#pragma unroll
        for (int j = 0; j < 8; j++) {
            KS[row][c * 8 + j] = bf2f(kv[j]);
            VS[row][c * 8 + j] = bf2f(vv[j]);
        }
    }
    __syncthreads();

    // Q row into registers
    float qreg[64];
    {
        const float* Qr = &KS[tl + 32][0];
#pragma unroll
        for (int k = 0; k < 64; k++) qreg[k] = Qr[k];
    }

    // scores for w in [qq*16, qq*16+16)
    float sv[16];
#pragma unroll
    for (int wi = 0; wi < 16; wi++) {
        int w = qq * 16 + wi;
        const float* Kr = &KS[tl + w][0];
        float acc = 0.f;
#pragma unroll
        for (int k = 0; k < 64; k++) acc += qreg[k] * Kr[k];
        sv[wi] = acc * 0.03125f;   // 1/sqrt(E) = 1/32
    }

    // softmax across the 4 quarters
    float lmax = sv[0];
#pragma unroll
    for (int wi = 1; wi < 16; wi++) lmax = fmaxf(lmax, sv[wi]);
    RED[tl][qq] = lmax;
    __syncthreads();
    float gmax = fmaxf(fmaxf(RED[tl][0], RED[tl][1]), fmaxf(RED[tl][2], RED[tl][3]));
    float lsum = 0.f;
#pragma unroll
    for (int wi = 0; wi < 16; wi++) {
        float e = __expf(sv[wi] - gmax);
        SC[tl][qq * 16 + wi] = e;
        lsum += e;
    }
    RED[tl][4 + qq] = lsum;
    __syncthreads();
    float gsum = RED[tl][4] + RED[tl][5] + RED[tl][6] + RED[tl][7];

    // PV: out d in [qq*16, qq*16+16)
    float oacc[16];
#pragma unroll
    for (int j = 0; j < 16; j++) oacc[j] = 0.f;
    for (int w = 0; w < 64; w++) {
        float p = SC[tl][w];
        const float* Vr = &VS[tl + w][qq * 16];
#pragma unroll
        for (int j = 0; j < 16; j++) oacc[j] += p * Vr[j];
    }

    float inv = 1.0f / gsum;
    size_t orow = ((size_t)b * NT + t0 + tl) * NE + h * 64 + qq * 16;
#pragma unroll
    for (int j = 0; j < 16; j++) M[orow + j] = f2bf(oacc[j] * inv);
}

// ---------------------------------------------------------------------------
extern "C" void kernel_launch(void* const* d_in, const int* in_sizes, int n_in,
                              void* d_out, int out_size, void* d_ws, size_t ws_size,
                              hipStream_t stream) {
    const float* x  = (const float*)d_in[0];
    // d_in[1] = position_mask: unused (window gather computed analytically)
    const float* Wq = (const float*)d_in[2];
    const float* bq = (const float*)d_in[3];
    const float* Wv = (const float*)d_in[4];
    const float* bv = (const float*)d_in[5];
    const float* Wo = (const float*)d_in[6];
    const float* bo = (const float*)d_in[7];
    float* outp = (float*)d_out;

    // workspace (bytes): Xb 4M | WTq 2M | WTv 2M | WTo 2M | Yb 4M | Zb 4M | Mb 4M
    char* wsb = (char*)d_ws;
    short* Xb  = (short*)(wsb);
    short* WTq = (short*)(wsb + (4u << 20));
    short* WTv = (short*)(wsb + (6u << 20));
    short* WTo = (short*)(wsb + (8u << 20));
    short* Yb  = (short*)(wsb + (10u << 20));
    short* Zb  = (short*)(wsb + (14u << 20));
    short* Mb  = (short*)(wsb + (18u << 20));

    cast_x_kernel<<<dim3(NBT * NE / (256 * 8)), 256, 0, stream>>>(x, Xb);
    transpose_w_kernel<true ><<<dim3(16, 16), 256, 0, stream>>>(Wq, WTq);
    transpose_w_kernel<true ><<<dim3(16, 16), 256, 0, stream>>>(Wv, WTv);
    transpose_w_kernel<false><<<dim3(16, 16), 256, 0, stream>>>(Wo, WTo);

    dim3 gg(NE / 128, NBT / 128);   // (8, 16)
    mfma_gemm_kernel<true,  true ><<<gg, 256, 0, stream>>>(Xb, WTq, bq, Yb);
    mfma_gemm_kernel<true,  true ><<<gg, 256, 0, stream>>>(Xb, WTv, bv, Zb);

    attn_kernel<<<dim3(NT / 64, NH, NB), 256, 0, stream>>>(Yb, Zb, Mb);

    mfma_gemm_kernel<false, false><<<gg, 256, 0, stream>>>(Mb, WTo, bo, (void*)outp);
}

// Round 4
// 174.551 us; speedup vs baseline: 3.5838x; 1.1957x over previous
//
#include <hip/hip_runtime.h>
#include <hip/hip_bf16.h>

typedef __attribute__((ext_vector_type(8))) short short8;
typedef __attribute__((ext_vector_type(4))) float f32x4;
typedef __attribute__((ext_vector_type(4))) unsigned int uint4v;

constexpr int NB = 4, NT = 512, NE = 1024, NW = 64, NH = 16, NDK = 64;
constexpr int NBT = NB * NT;   // 2048 token rows
constexpr int TT = 32;         // attn t-tile
constexpr int WIN = TT + 64;   // 96 staged window rows

__device__ inline short f2bf(float f) {
    __hip_bfloat16 h = __float2bfloat16(f);
    return __builtin_bit_cast(short, h);
}
__device__ inline float bf2f(short s) {
    unsigned u = ((unsigned)(unsigned short)s) << 16;
    return __builtin_bit_cast(float, u);
}
__device__ inline float blo(unsigned u) { return __builtin_bit_cast(float, u << 16); }
__device__ inline float bhi(unsigned u) { return __builtin_bit_cast(float, u & 0xffff0000u); }

// ---------------- cast x: f32 -> bf16 (row-major unchanged) ----------------
__global__ __launch_bounds__(256) void cast_x_kernel(const float* __restrict__ X,
                                                     short* __restrict__ Xb) {
    size_t idx = (size_t)blockIdx.x * 256 + threadIdx.x;   // 8 elems per thread
    const float4* p = (const float4*)(X + idx * 8);
    float4 a = p[0], b = p[1];
    short8 v;
    v[0] = f2bf(a.x); v[1] = f2bf(a.y); v[2] = f2bf(a.z); v[3] = f2bf(a.w);
    v[4] = f2bf(b.x); v[5] = f2bf(b.y); v[6] = f2bf(b.z); v[7] = f2bf(b.w);
    *(short8*)(Xb + idx * 8) = v;
}

// ------- cast+transpose all 3 W: f32 [E][N] -> bf16 [N][E]; Wq/Wv col-perm
// perm: output row jp = (j&15)*64 + (j>>4)   (j = d*16+h -> jp = h*64+d)
__global__ __launch_bounds__(256) void transpose_w_kernel(const float* __restrict__ W0,
                                                          const float* __restrict__ W1,
                                                          const float* __restrict__ W2,
                                                          short* __restrict__ WTall) {
    const float* W = blockIdx.z == 0 ? W0 : (blockIdx.z == 1 ? W1 : W2);
    const bool perm = blockIdx.z < 2;
    short* WT = WTall + (size_t)blockIdx.z * NE * NE;

    __shared__ float tile[64][65];
    const int e0 = blockIdx.y * 64, j0 = blockIdx.x * 64;
    const int el = threadIdx.x & 63, grp = threadIdx.x >> 6;
    for (int i = grp; i < 64; i += 4)
        tile[i][el] = W[(size_t)(e0 + i) * NE + j0 + el];
    __syncthreads();
    for (int it = grp; it < 64; it += 4) {
        int j = j0 + it;
        int jp = perm ? ((j & 15) * 64 + (j >> 4)) : j;
        WT[(size_t)jp * NE + e0 + el] = f2bf(tile[el][it]);
    }
}

// ---------------- MFMA GEMM: out[r][jp] = sum_e X[r][e]*WT[jp][e] + bias ----
// 64x64 tile, BK=64, 4 waves (each owns a 32x32 quadrant), grid 16x32=512.
template <bool PERM_BIAS, bool OUT_BF16>
__global__ __launch_bounds__(256) void mfma_gemm_kernel(const short* __restrict__ X,
                                                        const short* __restrict__ WT,
                                                        const float* __restrict__ bias,
                                                        void* __restrict__ outv) {
    __shared__ short As[64 * 64];
    __shared__ short Bs[64 * 64];
    const int tid = threadIdx.x;
    const int lane = tid & 63, wid = tid >> 6;

    // bijective XCD swizzle over 512 blocks (grid fixed at 16 x 32)
    int bid = blockIdx.y * 16 + blockIdx.x;
    int swz = (bid & 7) * 64 + (bid >> 3);
    const int r0 = (swz >> 4) * 64;        // M block
    const int c0 = (swz & 15) * 64;        // N block
    const int wr = (wid >> 1) * 32, wc = (wid & 1) * 32;

    f32x4 acc[2][2];
#pragma unroll
    for (int m = 0; m < 2; m++)
#pragma unroll
        for (int n = 0; n < 2; n++) acc[m][n] = (f32x4){0.f, 0.f, 0.f, 0.f};

    short8 pfA[2], pfB[2];
    // LDS tile: row-major [64][64] bf16, 16B chunk c stored at c ^ (row&7)
    auto load_tiles = [&](int k0) {
#pragma unroll
        for (int rd = 0; rd < 2; rd++) {
            int slot = rd * 4096 + tid * 16;       // byte offset in 8KB tile
            int row  = slot >> 7;                  // /128B
            int cp   = (slot >> 4) & 7;
            int c    = cp ^ (row & 7);
            pfA[rd] = *(const short8*)(X  + (size_t)(r0 + row) * NE + k0 + c * 8);
            pfB[rd] = *(const short8*)(WT + (size_t)(c0 + row) * NE + k0 + c * 8);
        }
    };

    load_tiles(0);
    for (int k0 = 0; k0 < NE; k0 += 64) {
        __syncthreads();   // previous compute done before overwrite
#pragma unroll
        for (int rd = 0; rd < 2; rd++) {
            int slot = rd * 4096 + tid * 16;
            *(short8*)((char*)As + slot) = pfA[rd];
            *(short8*)((char*)Bs + slot) = pfB[rd];
        }
        __syncthreads();
        if (k0 + 64 < NE) load_tiles(k0 + 64);   // prefetch hides under MFMA

#pragma unroll
        for (int kk = 0; kk < 2; kk++) {
            short8 af[2], bf[2];
            const int cidx = kk * 4 + (lane >> 4);
#pragma unroll
            for (int m = 0; m < 2; m++) {
                int row = wr + m * 16 + (lane & 15);
                af[m] = *(const short8*)((char*)As + row * 128 + ((cidx ^ (row & 7)) * 16));
            }
#pragma unroll
            for (int n = 0; n < 2; n++) {
                int row = wc + n * 16 + (lane & 15);
                bf[n] = *(const short8*)((char*)Bs + row * 128 + ((cidx ^ (row & 7)) * 16));
            }
#pragma unroll
            for (int m = 0; m < 2; m++)
#pragma unroll
                for (int n = 0; n < 2; n++)
                    acc[m][n] = __builtin_amdgcn_mfma_f32_16x16x32_bf16(af[m], bf[n], acc[m][n], 0, 0, 0);
        }
    }

    short* outS = (short*)outv;
    float* outF = (float*)outv;
#pragma unroll
    for (int m = 0; m < 2; m++)
#pragma unroll
        for (int n = 0; n < 2; n++) {
            int col  = c0 + wc + n * 16 + (lane & 15);
            int bsrc = PERM_BIAS ? ((col & 63) * 16 + (col >> 6)) : col;
            float bb = bias[bsrc];
#pragma unroll
            for (int r = 0; r < 4; r++) {
                int row = r0 + wr + m * 16 + (lane >> 4) * 4 + r;
                float val = acc[m][n][r] + bb;
                if (OUT_BF16) outS[(size_t)row * NE + col] = f2bf(val);
                else          outF[(size_t)row * NE + col] = val;
            }
        }
}

// ---------------- windowed attention, head-major layout, bf16 LDS ----------
// Y,Z bf16 [B*T][NE], column jp = h*64+d. Block = (t-tile 32, h, b); 1024 blocks.
// Thread (tl, oct): QK for 8 w's; PV for 8 d's. K window also serves Q rows.
__global__ __launch_bounds__(256) void attn_kernel(const short* __restrict__ Y,
                                                   const short* __restrict__ Z,
                                                   short* __restrict__ M) {
    __shared__ short KS[WIN][66];   // stride 132B -> bank = row%32, conflict-free
    __shared__ short VS[WIN][66];
    __shared__ short SCb[TT][66];   // probs (bf16)
    __shared__ float RED[TT][16];   // [0..7] max partials, [8..15] sum partials

    const int t0 = blockIdx.x * TT;
    const int h  = blockIdx.y;
    const int b  = blockIdx.z;
    const int tid = threadIdx.x;
    const int tl  = tid & (TT - 1);
    const int oct = tid >> 5;       // 0..7

    // stage K (= Y rows; also Q) and V windows: WIN rows x 64 d (bf16)
    for (int idx = tid; idx < WIN * 8; idx += 256) {
        int row = idx >> 3, c = idx & 7;
        int ts = t0 - 32 + row;
        ts = ts < 0 ? 0 : (ts > NT - 1 ? NT - 1 : ts);
        size_t base = ((size_t)b * NT + ts) * NE + h * 64 + c * 8;
        uint4v ku = __builtin_bit_cast(uint4v, *(const short8*)(Y + base));
        uint4v vu = __builtin_bit_cast(uint4v, *(const short8*)(Z + base));
        unsigned* kd = (unsigned*)&KS[row][c * 8];
        unsigned* vd = (unsigned*)&VS[row][c * 8];
        kd[0] = ku[0]; kd[1] = ku[1]; kd[2] = ku[2]; kd[3] = ku[3];
        vd[0] = vu[0]; vd[1] = vu[1]; vd[2] = vu[2]; vd[3] = vu[3];
    }
    __syncthreads();

    // Q row (window index tl+32) into f32 registers
    float q[64];
    {
        const unsigned* Qr = (const unsigned*)&KS[tl + 32][0];
#pragma unroll
        for (int k2 = 0; k2 < 32; k2++) {
            unsigned u = Qr[k2];
            q[2 * k2]     = blo(u);
            q[2 * k2 + 1] = bhi(u);
        }
    }

    // scores for w in [oct*8, oct*8+8)
    float sv[8];
#pragma unroll
    for (int wi = 0; wi < 8; wi++) {
        int w = oct * 8 + wi;
        const unsigned* Kr = (const unsigned*)&KS[tl + w][0];
        float acc = 0.f;
#pragma unroll
        for (int k2 = 0; k2 < 32; k2++) {
            unsigned u = Kr[k2];
            acc += q[2 * k2] * blo(u) + q[2 * k2 + 1] * bhi(u);
        }
        sv[wi] = acc * 0.03125f;   // 1/sqrt(E) = 1/32
    }

    // softmax across the 8 octs
    float lmax = sv[0];
#pragma unroll
    for (int wi = 1; wi < 8; wi++) lmax = fmaxf(lmax, sv[wi]);
    RED[tl][oct] = lmax;
    __syncthreads();
    float gmax = RED[tl][0];
#pragma unroll
    for (int i = 1; i < 8; i++) gmax = fmaxf(gmax, RED[tl][i]);
    float lsum = 0.f;
#pragma unroll
    for (int wi = 0; wi < 8; wi++) {
        float e = __expf(sv[wi] - gmax);
        SCb[tl][oct * 8 + wi] = f2bf(e);
        lsum += e;
    }
    RED[tl][8 + oct] = lsum;
    __syncthreads();
    float gsum = RED[tl][8];
#pragma unroll
    for (int i = 9; i < 16; i++) gsum += RED[tl][i];

    // PV: out d in [oct*8, oct*8+8)
    float oacc[8];
#pragma unroll
    for (int j = 0; j < 8; j++) oacc[j] = 0.f;
    for (int w = 0; w < NW; w++) {
        float p = bf2f(SCb[tl][w]);
        const unsigned* Vr = (const unsigned*)&VS[tl + w][oct * 8];
#pragma unroll
        for (int j2 = 0; j2 < 4; j2++) {
            unsigned u = Vr[j2];
            oacc[2 * j2]     += p * blo(u);
            oacc[2 * j2 + 1] += p * bhi(u);
        }
    }

    float inv = 1.0f / gsum;
    short8 ov;
#pragma unroll
    for (int j = 0; j < 8; j++) ov[j] = f2bf(oacc[j] * inv);
    size_t orow = ((size_t)b * NT + t0 + tl) * NE + h * 64 + oct * 8;
    *(short8*)(M + orow) = ov;
}

// ---------------------------------------------------------------------------
extern "C" void kernel_launch(void* const* d_in, const int* in_sizes, int n_in,
                              void* d_out, int out_size, void* d_ws, size_t ws_size,
                              hipStream_t stream) {
    const float* x  = (const float*)d_in[0];
    // d_in[1] = position_mask: unused (window gather computed analytically)
    const float* Wq = (const float*)d_in[2];
    const float* bq = (const float*)d_in[3];
    const float* Wv = (const float*)d_in[4];
    const float* bv = (const float*)d_in[5];
    const float* Wo = (const float*)d_in[6];
    const float* bo = (const float*)d_in[7];
    float* outp = (float*)d_out;

    // workspace: Xb 4M | WTall 6M (Wq,Wv,Wo) | Yb 4M | Zb 4M | Mb 4M
    char* wsb = (char*)d_ws;
    short* Xb  = (short*)(wsb);
    short* WTa = (short*)(wsb + (4u << 20));
    short* Yb  = (short*)(wsb + (10u << 20));
    short* Zb  = (short*)(wsb + (14u << 20));
    short* Mb  = (short*)(wsb + (18u << 20));
    short* WTq = WTa;
    short* WTv = WTa + (size_t)NE * NE;
    short* WTo = WTv + (size_t)NE * NE;

    cast_x_kernel<<<dim3(NBT * NE / (256 * 8)), 256, 0, stream>>>(x, Xb);
    transpose_w_kernel<<<dim3(16, 16, 3), 256, 0, stream>>>(Wq, Wv, Wo, WTa);

    dim3 gg(NE / 64, NBT / 64);   // (16, 32) = 512 blocks
    mfma_gemm_kernel<true,  true ><<<gg, 256, 0, stream>>>(Xb, WTq, bq, Yb);
    mfma_gemm_kernel<true,  true ><<<gg, 256, 0, stream>>>(Xb, WTv, bv, Zb);

    attn_kernel<<<dim3(NT / TT, NH, NB), 256, 0, stream>>>(Yb, Zb, Mb);

    mfma_gemm_kernel<false, false><<<gg, 256, 0, stream>>>(Mb, WTo, bo, (void*)outp);
}

// Round 5
// 168.803 us; speedup vs baseline: 3.7058x; 1.0341x over previous
//
#include <hip/hip_runtime.h>
#include <hip/hip_bf16.h>

typedef __attribute__((ext_vector_type(8))) short short8;
typedef __attribute__((ext_vector_type(4))) float f32x4;
typedef __attribute__((ext_vector_type(4))) unsigned int uint4v;

constexpr int NB = 4, NT = 512, NE = 1024, NW = 64, NH = 16, NDK = 64;
constexpr int NBT = NB * NT;   // 2048 token rows
constexpr int TT = 32;         // attn t-tile
constexpr int WIN = TT + 64;   // 96 staged window rows

__device__ inline short f2bf(float f) {
    __hip_bfloat16 h = __float2bfloat16(f);
    return __builtin_bit_cast(short, h);
}
__device__ inline float bf2f(short s) {
    unsigned u = ((unsigned)(unsigned short)s) << 16;
    return __builtin_bit_cast(float, u);
}
__device__ inline float blo(unsigned u) { return __builtin_bit_cast(float, u << 16); }
__device__ inline float bhi(unsigned u) { return __builtin_bit_cast(float, u & 0xffff0000u); }

// ---------------- cast x: f32 -> bf16 (row-major unchanged) ----------------
__global__ __launch_bounds__(256) void cast_x_kernel(const float* __restrict__ X,
                                                     short* __restrict__ Xb) {
    size_t idx = (size_t)blockIdx.x * 256 + threadIdx.x;   // 8 elems per thread
    const float4* p = (const float4*)(X + idx * 8);
    float4 a = p[0], b = p[1];
    short8 v;
    v[0] = f2bf(a.x); v[1] = f2bf(a.y); v[2] = f2bf(a.z); v[3] = f2bf(a.w);
    v[4] = f2bf(b.x); v[5] = f2bf(b.y); v[6] = f2bf(b.z); v[7] = f2bf(b.w);
    *(short8*)(Xb + idx * 8) = v;
}

// ------- cast+transpose all 3 W: f32 [E][N] -> bf16 [N][E]; Wq/Wv col-perm
// perm: output row jp = (j&15)*64 + (j>>4)   (j = d*16+h -> jp = h*64+d)
__global__ __launch_bounds__(256) void transpose_w_kernel(const float* __restrict__ W0,
                                                          const float* __restrict__ W1,
                                                          const float* __restrict__ W2,
                                                          short* __restrict__ WTall) {
    const float* W = blockIdx.z == 0 ? W0 : (blockIdx.z == 1 ? W1 : W2);
    const bool perm = blockIdx.z < 2;
    short* WT = WTall + (size_t)blockIdx.z * NE * NE;

    __shared__ float tile[64][65];
    const int e0 = blockIdx.y * 64, j0 = blockIdx.x * 64;
    const int el = threadIdx.x & 63, grp = threadIdx.x >> 6;
    for (int i = grp; i < 64; i += 4)
        tile[i][el] = W[(size_t)(e0 + i) * NE + j0 + el];
    __syncthreads();
    for (int it = grp; it < 64; it += 4) {
        int j = j0 + it;
        int jp = perm ? ((j & 15) * 64 + (j >> 4)) : j;
        WT[(size_t)jp * NE + e0 + el] = f2bf(tile[el][it]);
    }
}

// ---------------- MFMA GEMM: out[r][jp] = sum_e X[r][e]*WT[jp][e] + bias ----
// BM x BN tile, BK=64, 4 waves in 2x2 (each owns BM/2 x BN/2), reg-staged
// prefetch, XOR-swizzled LDS (16B chunk c stored at c ^ (row&7)).
// DUAL: B rows = concat(WT0 rows, WT1 rows) (N_eff = 2*NE); the c0>=NE half
// writes out1/bias1. Grid: (N_eff/BN, NBT/BM), product must be %8==0.
template <int BM, int BN, int LOG_GX, bool PERM_BIAS, bool OUT_BF16, bool DUAL>
__global__ __launch_bounds__(256) void mfma_gemm_kernel(const short* __restrict__ X,
                                                        const short* __restrict__ WT,
                                                        const float* __restrict__ bias0,
                                                        const float* __restrict__ bias1,
                                                        void* __restrict__ out0,
                                                        void* __restrict__ out1) {
    constexpr int MR = BM / 32, NR = BN / 32;       // per-wave 16x16 frags
    constexpr int RDA = BM / 32, RDB = BN / 32;     // staging loads per thread

    __shared__ short As[BM * 64];
    __shared__ short Bs[BN * 64];
    const int tid = threadIdx.x;
    const int lane = tid & 63, wid = tid >> 6;

    // bijective XCD swizzle (nwg % 8 == 0)
    const int nwg = (1 << LOG_GX) * gridDim.y;
    const int bid = blockIdx.y * (1 << LOG_GX) + blockIdx.x;
    const int swz = (bid & 7) * (nwg >> 3) + (bid >> 3);
    const int r0 = (swz >> LOG_GX) * BM;
    const int c0 = (swz & ((1 << LOG_GX) - 1)) * BN;
    const int wr = (wid >> 1) * (BM / 2), wc = (wid & 1) * (BN / 2);

    f32x4 acc[MR][NR];
#pragma unroll
    for (int m = 0; m < MR; m++)
#pragma unroll
        for (int n = 0; n < NR; n++) acc[m][n] = (f32x4){0.f, 0.f, 0.f, 0.f};

    short8 pfA[RDA], pfB[RDB];
    auto load_tiles = [&](int k0) {
#pragma unroll
        for (int rd = 0; rd < RDA; rd++) {
            int slot = rd * 4096 + tid * 16;       // byte offset in A tile
            int row  = slot >> 7;                  // /128B
            int c    = ((slot >> 4) & 7) ^ (row & 7);
            pfA[rd] = *(const short8*)(X + (size_t)(r0 + row) * NE + k0 + c * 8);
        }
#pragma unroll
        for (int rd = 0; rd < RDB; rd++) {
            int slot = rd * 4096 + tid * 16;
            int row  = slot >> 7;
            int c    = ((slot >> 4) & 7) ^ (row & 7);
            pfB[rd] = *(const short8*)(WT + (size_t)(c0 + row) * NE + k0 + c * 8);
        }
    };

    load_tiles(0);
    for (int k0 = 0; k0 < NE; k0 += 64) {
        __syncthreads();   // previous compute done before overwrite
#pragma unroll
        for (int rd = 0; rd < RDA; rd++)
            *(short8*)((char*)As + rd * 4096 + tid * 16) = pfA[rd];
#pragma unroll
        for (int rd = 0; rd < RDB; rd++)
            *(short8*)((char*)Bs + rd * 4096 + tid * 16) = pfB[rd];
        __syncthreads();
        if (k0 + 64 < NE) load_tiles(k0 + 64);   // prefetch hides under MFMA

#pragma unroll
        for (int kk = 0; kk < 2; kk++) {
            short8 af[MR], bf[NR];
            const int cidx = kk * 4 + (lane >> 4);
#pragma unroll
            for (int m = 0; m < MR; m++) {
                int row = wr + m * 16 + (lane & 15);
                af[m] = *(const short8*)((char*)As + row * 128 + ((cidx ^ (row & 7)) * 16));
            }
#pragma unroll
            for (int n = 0; n < NR; n++) {
                int row = wc + n * 16 + (lane & 15);
                bf[n] = *(const short8*)((char*)Bs + row * 128 + ((cidx ^ (row & 7)) * 16));
            }
#pragma unroll
            for (int m = 0; m < MR; m++)
#pragma unroll
                for (int n = 0; n < NR; n++)
                    acc[m][n] = __builtin_amdgcn_mfma_f32_16x16x32_bf16(af[m], bf[n], acc[m][n], 0, 0, 0);
        }
    }

    const float* bias = bias0;
    void* outv = out0;
    int cbase = c0;
    if (DUAL && c0 >= NE) { bias = bias1; outv = out1; cbase = c0 - NE; }
    short* outS = (short*)outv;
    float* outF = (float*)outv;
#pragma unroll
    for (int m = 0; m < MR; m++)
#pragma unroll
        for (int n = 0; n < NR; n++) {
            int lc   = cbase + wc + n * 16 + (lane & 15);
            int bsrc = PERM_BIAS ? ((lc & 63) * 16 + (lc >> 6)) : lc;
            float bb = bias[bsrc];
#pragma unroll
            for (int r = 0; r < 4; r++) {
                int row = r0 + wr + m * 16 + (lane >> 4) * 4 + r;
                float val = acc[m][n][r] + bb;
                if (OUT_BF16) outS[(size_t)row * NE + lc] = f2bf(val);
                else          outF[(size_t)row * NE + lc] = val;
            }
        }
}

// ---------------- windowed attention, head-major layout, bf16 LDS ----------
// Y,Z bf16 [B*T][NE], column jp = h*64+d. Block = (t-tile 32, h, b); 1024 blocks.
// Thread (tl, oct): QK for 8 w's; PV for 8 d's. K window also serves Q rows.
__global__ __launch_bounds__(256) void attn_kernel(const short* __restrict__ Y,
                                                   const short* __restrict__ Z,
                                                   short* __restrict__ M) {
    __shared__ short KS[WIN][66];   // stride 132B -> bank = row%32, conflict-free
    __shared__ short VS[WIN][66];
    __shared__ short SCb[TT][66];   // probs (bf16)
    __shared__ float RED[TT][16];   // [0..7] max partials, [8..15] sum partials

    const int t0 = blockIdx.x * TT;
    const int h  = blockIdx.y;
    const int b  = blockIdx.z;
    const int tid = threadIdx.x;
    const int tl  = tid & (TT - 1);
    const int oct = tid >> 5;       // 0..7

    // stage K (= Y rows; also Q) and V windows: WIN rows x 64 d (bf16)
    for (int idx = tid; idx < WIN * 8; idx += 256) {
        int row = idx >> 3, c = idx & 7;
        int ts = t0 - 32 + row;
        ts = ts < 0 ? 0 : (ts > NT - 1 ? NT - 1 : ts);
        size_t base = ((size_t)b * NT + ts) * NE + h * 64 + c * 8;
        uint4v ku = __builtin_bit_cast(uint4v, *(const short8*)(Y + base));
        uint4v vu = __builtin_bit_cast(uint4v, *(const short8*)(Z + base));
        unsigned* kd = (unsigned*)&KS[row][c * 8];
        unsigned* vd = (unsigned*)&VS[row][c * 8];
        kd[0] = ku[0]; kd[1] = ku[1]; kd[2] = ku[2]; kd[3] = ku[3];
        vd[0] = vu[0]; vd[1] = vu[1]; vd[2] = vu[2]; vd[3] = vu[3];
    }
    __syncthreads();

    // Q row (window index tl+32) into f32 registers
    float q[64];
    {
        const unsigned* Qr = (const unsigned*)&KS[tl + 32][0];
#pragma unroll
        for (int k2 = 0; k2 < 32; k2++) {
            unsigned u = Qr[k2];
            q[2 * k2]     = blo(u);
            q[2 * k2 + 1] = bhi(u);
        }
    }

    // scores for w in [oct*8, oct*8+8)
    float sv[8];
#pragma unroll
    for (int wi = 0; wi < 8; wi++) {
        int w = oct * 8 + wi;
        const unsigned* Kr = (const unsigned*)&KS[tl + w][0];
        float acc = 0.f;
#pragma unroll
        for (int k2 = 0; k2 < 32; k2++) {
            unsigned u = Kr[k2];
            acc += q[2 * k2] * blo(u) + q[2 * k2 + 1] * bhi(u);
        }
        sv[wi] = acc * 0.03125f;   // 1/sqrt(E) = 1/32
    }

    // softmax across the 8 octs
    float lmax = sv[0];
#pragma unroll
    for (int wi = 1; wi < 8; wi++) lmax = fmaxf(lmax, sv[wi]);
    RED[tl][oct] = lmax;
    __syncthreads();
    float gmax = RED[tl][0];
#pragma unroll
    for (int i = 1; i < 8; i++) gmax = fmaxf(gmax, RED[tl][i]);
    float lsum = 0.f;
#pragma unroll
    for (int wi = 0; wi < 8; wi++) {
        float e = __expf(sv[wi] - gmax);
        SCb[tl][oct * 8 + wi] = f2bf(e);
        lsum += e;
    }
    RED[tl][8 + oct] = lsum;
    __syncthreads();
    float gsum = RED[tl][8];
#pragma unroll
    for (int i = 9; i < 16; i++) gsum += RED[tl][i];

    // PV: out d in [oct*8, oct*8+8)
    float oacc[8];
#pragma unroll
    for (int j = 0; j < 8; j++) oacc[j] = 0.f;
    for (int w = 0; w < NW; w++) {
        float p = bf2f(SCb[tl][w]);
        const unsigned* Vr = (const unsigned*)&VS[tl + w][oct * 8];
#pragma unroll
        for (int j2 = 0; j2 < 4; j2++) {
            unsigned u = Vr[j2];
            oacc[2 * j2]     += p * blo(u);
            oacc[2 * j2 + 1] += p * bhi(u);
        }
    }

    float inv = 1.0f / gsum;
    short8 ov;
#pragma unroll
    for (int j = 0; j < 8; j++) ov[j] = f2bf(oacc[j] * inv);
    size_t orow = ((size_t)b * NT + t0 + tl) * NE + h * 64 + oct * 8;
    *(short8*)(M + orow) = ov;
}

// ---------------------------------------------------------------------------
extern "C" void kernel_launch(void* const* d_in, const int* in_sizes, int n_in,
                              void* d_out, int out_size, void* d_ws, size_t ws_size,
                              hipStream_t stream) {
    const float* x  = (const float*)d_in[0];
    // d_in[1] = position_mask: unused (window gather computed analytically)
    const float* Wq = (const float*)d_in[2];
    const float* bq = (const float*)d_in[3];
    const float* Wv = (const float*)d_in[4];
    const float* bv = (const float*)d_in[5];
    const float* Wo = (const float*)d_in[6];
    const float* bo = (const float*)d_in[7];
    float* outp = (float*)d_out;

    // workspace: Xb 4M | WTall 6M (Wq,Wv,Wo contiguous) | Yb 4M | Zb 4M | Mb 4M
    char* wsb = (char*)d_ws;
    short* Xb  = (short*)(wsb);
    short* WTa = (short*)(wsb + (4u << 20));
    short* Yb  = (short*)(wsb + (10u << 20));
    short* Zb  = (short*)(wsb + (14u << 20));
    short* Mb  = (short*)(wsb + (18u << 20));
    short* WTo = WTa + 2 * (size_t)NE * NE;

    cast_x_kernel<<<dim3(NBT * NE / (256 * 8)), 256, 0, stream>>>(x, Xb);
    transpose_w_kernel<<<dim3(16, 16, 3), 256, 0, stream>>>(Wq, Wv, Wo, WTa);

    // fused Q/V projection: B = concat(WTq, WTv), N_eff = 2048 -> grid (16,16)
    mfma_gemm_kernel<128, 128, 4, true, true, true>
        <<<dim3(2 * NE / 128, NBT / 128), 256, 0, stream>>>(Xb, WTa, bq, bv, Yb, Zb);

    attn_kernel<<<dim3(NT / TT, NH, NB), 256, 0, stream>>>(Yb, Zb, Mb);

    // output projection: 64x128 tile -> grid (8,32) = 256 blocks
    mfma_gemm_kernel<64, 128, 3, false, false, false>
        <<<dim3(NE / 128, NBT / 64), 256, 0, stream>>>(Mb, WTo, bo, nullptr, (void*)outp, nullptr);
}